// Round 9
// baseline (500.106 us; speedup 1.0000x reference)
//
#include <hip/hip_runtime.h>
#include <hip/hip_bf16.h>

typedef unsigned short u16;
typedef unsigned int u32;
typedef __attribute__((ext_vector_type(8))) short s16x8;
typedef __attribute__((ext_vector_type(4))) short s16x4;
typedef __attribute__((ext_vector_type(4))) float f32x4;

__device__ inline u16 f2bf(float x) {
    u32 u = __float_as_uint(x);
    u32 r = (u + 0x7fffu + ((u >> 16) & 1u)) >> 16;
    return (u16)r;
}
__device__ inline float bf2f(u16 u) {
    return __uint_as_float(((u32)u) << 16);
}

// ---- features f32 -> bf16, with zero sentinel row at index N ----
__global__ void k_feat2bf(const float* __restrict__ f, u16* __restrict__ o,
                          int total, int nvalid) {
    int i = (blockIdx.x * 256 + threadIdx.x) * 8;
    if (i >= total) return;
    s16x8 v;
#pragma unroll
    for (int j = 0; j < 8; ++j) {
        float x = (i + j < nvalid) ? f[i + j] : 0.f;
        v[j] = (short)f2bf(x);
    }
    *(s16x8*)(o + i) = v;
}

// ---- weight swizzle: W[9][cin][128] f32 -> MFMA-B fragment-packed bf16 ----
// frag fr = (tap*KC + kc)*8 + ct ; lane l holds 8 bf16 at fr*512 + l*8,
// element j = W[tap][kc*32 + (l>>4)*8 + j][ct*16 + (l&15)]
__global__ void k_swz(const float* __restrict__ W, u16* __restrict__ o, int cin) {
    int i = blockIdx.x * 256 + threadIdx.x;
    int total = 9 * cin * 128;
    if (i >= total) return;
    int j = i & 7;
    int l = (i >> 3) & 63;
    int fr = i >> 9;
    int ct = fr & 7;
    int rest = fr >> 3;
    int kcn = cin >> 5;
    int kc = rest % kcn;
    int t = rest / kcn;
    int kk = kc * 32 + (l >> 4) * 8 + j;
    int c = ct * 16 + (l & 15);
    o[i] = f2bf(W[(t * cin + kk) * 128 + c]);
}

// ---- gather-conv: block = 512 thr = 8 waves; 64 voxels x 128 cols.
// wave: 32 vox (vhalf = wv>>2) x 32 cols (col-tile = wv&3). NO weight LDS:
// B-frags are wave-uniform 1KB loads -> L2-broadcast resident. Gathers are
// issued once per block's 64 vox (4 col-waves' duplicates coalesce in L1).
// Rolling 2-tap nbr prefetch + batch per-tap A loads; pair-level tap skip.
template <int CIN>
__global__ __launch_bounds__(512, 7) void k_conv(
    const u16* __restrict__ srcA, const u16* __restrict__ srcB,
    const int* __restrict__ nbrA, const int* __restrict__ nbrB,
    const u16* __restrict__ wA, const u16* __restrict__ wB,
    u16* __restrict__ zoutA, u16* __restrict__ zoutB,
    float* __restrict__ statsA, float* __restrict__ statsB,
    int N) {
    constexpr int KC = CIN / 32;
    __shared__ float sstat[256];

    const int tid = threadIdx.x;
    const int cz = blockIdx.y;
    const u16* __restrict__ src = cz ? srcB : srcA;
    const int* __restrict__ nbr = cz ? nbrB : nbrA;
    const u16* __restrict__ w = cz ? wB : wA;
    u16* __restrict__ zout = cz ? zoutB : zoutA;
    float* __restrict__ stats = cz ? statsB : statsA;

    if (tid < 256) sstat[tid] = 0.f;
    __syncthreads();

    const int lane = tid & 63;
    const int wv = tid >> 6;          // 0..7
    const int ctile = wv & 3;         // which 32-col tile
    const int vhalf = wv >> 2;        // which 32-vox half
    const int base = blockIdx.x * 64 + vhalf * 32;
    const int am = lane & 15;
    const int grp = lane >> 4;
    const int vi0 = base + am;
    const int vi1 = base + 16 + am;
    const bool v0 = vi0 < N, v1 = vi1 < N;

    f32x4 acc0[2], acc1[2];
#pragma unroll
    for (int c = 0; c < 2; ++c) {
        acc0[c] = (f32x4){0.f, 0.f, 0.f, 0.f};
        acc1[c] = (f32x4){0.f, 0.f, 0.f, 0.f};
    }

    int rc0 = v0 ? nbr[vi0] : N;
    int rc1 = v1 ? nbr[vi1] : N;

#pragma unroll
    for (int t = 0; t < 9; ++t) {
        // prefetch next tap's nbr indices (in flight during compute)
        int rn0 = N, rn1 = N;
        if (t < 8) {
            if (v0) rn0 = nbr[(t + 1) * N + vi0];
            if (v1) rn1 = nbr[(t + 1) * N + vi1];
        }
        if (__any((rc0 != N) || (rc1 != N))) {
            const u16* sp0 = src + (size_t)rc0 * CIN + grp * 8;
            const u16* sp1 = src + (size_t)rc1 * CIN + grp * 8;
            // batch all A-gathers for this tap (one latency wait)
            s16x8 a0[KC], a1[KC];
#pragma unroll
            for (int kc = 0; kc < KC; ++kc) {
                a0[kc] = *(const s16x8*)(sp0 + kc * 32);
                a1[kc] = *(const s16x8*)(sp1 + kc * 32);
            }
            // B-frags straight from global (uniform address -> L2 broadcast)
            const u16* wp = w + ((size_t)(t * KC) * 8 + ctile * 2) * 512 + lane * 8;
#pragma unroll
            for (int kc = 0; kc < KC; ++kc) {
#pragma unroll
                for (int c = 0; c < 2; ++c) {
                    s16x8 b = *(const s16x8*)(wp + (size_t)(kc * 8 + c) * 512);
                    acc0[c] = __builtin_amdgcn_mfma_f32_16x16x32_bf16(a0[kc], b, acc0[c], 0, 0, 0);
                    acc1[c] = __builtin_amdgcn_mfma_f32_16x16x32_bf16(a1[kc], b, acc1[c], 0, 0, 0);
                }
            }
        }
        rc0 = rn0;
        rc1 = rn1;
    }

    // epilogue: lrelu, bf16 store, block-local stats
#pragma unroll
    for (int c = 0; c < 2; ++c) {
        float s = 0.f, qq = 0.f;
        const int col = ctile * 32 + c * 16 + am;
#pragma unroll
        for (int j = 0; j < 4; ++j) {
            {
                float x = acc0[c][j];
                float z = (x > 0.f) ? x : 0.01f * x;
                int row = base + grp * 4 + j;
                if (row < N) zout[(size_t)row * 128 + col] = f2bf(z);
                s += z;
                qq += z * z;
            }
            {
                float x = acc1[c][j];
                float z = (x > 0.f) ? x : 0.01f * x;
                int row = base + 16 + grp * 4 + j;
                if (row < N) zout[(size_t)row * 128 + col] = f2bf(z);
                s += z;
                qq += z * z;
            }
        }
        s += __shfl_xor(s, 16);
        qq += __shfl_xor(qq, 16);
        s += __shfl_xor(s, 32);
        qq += __shfl_xor(qq, 32);
        if (lane < 16) {
            atomicAdd(&sstat[col], s);
            atomicAdd(&sstat[128 + col], qq);
        }
    }
    __syncthreads();
    if (tid < 128) {
        atomicAdd(stats + tid, sstat[tid]);
        atomicAdd(stats + 128 + tid, sstat[128 + tid]);
    }
}

// ---- finalize two BN stat sets -> per-channel scale/shift ----
__global__ void k_fin(const float* __restrict__ stats,
                      const float* __restrict__ g0, const float* __restrict__ b0,
                      const float* __restrict__ g1, const float* __restrict__ b1,
                      float* __restrict__ ss, int N) {
    int tid = threadIdx.x;
    int set = tid >> 7, c = tid & 127;
    const float* st = stats + set * 256;
    float invN = 1.f / (float)N;
    float m = st[c] * invN;
    float var = st[128 + c] * invN - m * m;
    const float* g = set ? g1 : g0;
    const float* b = set ? b1 : b0;
    float sc = g[c] * rsqrtf(var + 1e-5f);
    float sh = b[c] - m * sc;
    float* o = ss + set * 256;
    o[c] = sc;
    o[128 + c] = sh;
}

// ---- y = z*scale + shift (bf16 out, with zero sentinel row N) ----
__global__ void k_aff(const u16* __restrict__ z, const float* __restrict__ ss,
                      u16* __restrict__ y, int N) {
    int v = blockIdx.x * 256 + threadIdx.x;
    int total = (N + 1) * 16;
    if (v >= total) return;
    int row = v >> 4;
    int cb = (v & 15) * 8;
    s16x8 o;
    if (row < N) {
        s16x8 zi = *(const s16x8*)(z + (size_t)row * 128 + cb);
#pragma unroll
        for (int j = 0; j < 8; ++j) {
            float x = bf2f((u16)zi[j]);
            float r = x * ss[cb + j] + ss[128 + cb + j];
            o[j] = (short)f2bf(r);
        }
    } else {
        o = (s16x8){0, 0, 0, 0, 0, 0, 0, 0};
    }
    *(s16x8*)(y + (size_t)row * 128 + cb) = o;
}

// ---- out = bn(z3) + bn(z4), f32 ----
__global__ void k_final(const u16* __restrict__ z3, const u16* __restrict__ z4,
                        const float* __restrict__ ssA, const float* __restrict__ ssB,
                        float* __restrict__ out, int N) {
    int v = blockIdx.x * 256 + threadIdx.x;
    int total = N * 32;
    if (v >= total) return;
    int row = v >> 5;
    int cb = (v & 31) * 4;
    s16x4 a = *(const s16x4*)(z3 + (size_t)row * 128 + cb);
    s16x4 b = *(const s16x4*)(z4 + (size_t)row * 128 + cb);
    f32x4 o;
#pragma unroll
    for (int j = 0; j < 4; ++j) {
        int c = cb + j;
        o[j] = bf2f((u16)a[j]) * ssA[c] + ssA[128 + c] +
               bf2f((u16)b[j]) * ssB[c] + ssB[128 + c];
    }
    *(f32x4*)(out + (size_t)row * 128 + cb) = o;
}

extern "C" void kernel_launch(void* const* d_in, const int* in_sizes, int n_in,
                              void* d_out, int out_size, void* d_ws, size_t ws_size,
                              hipStream_t stream) {
    const float* feat = (const float*)d_in[0];
    const int* nbr31 = (const int*)d_in[1];
    const int* nbr13 = (const int*)d_in[2];
    const float* W1 = (const float*)d_in[3];
    const float* W12 = (const float*)d_in[4];
    const float* W2 = (const float*)d_in[5];
    const float* W3 = (const float*)d_in[6];
    const float* g0 = (const float*)d_in[7];
    const float* b0 = (const float*)d_in[8];
    const float* g02 = (const float*)d_in[9];
    const float* b02 = (const float*)d_in[10];
    const float* g1 = (const float*)d_in[11];
    const float* b1 = (const float*)d_in[12];
    const float* g2 = (const float*)d_in[13];
    const float* b2 = (const float*)d_in[14];
    float* out = (float*)d_out;
    const int N = in_sizes[0] / 64;  // 200000

    char* p = (char*)d_ws;
    auto alloc = [&](size_t bytes) {
        char* r = p;
        p += (bytes + 255) & ~(size_t)255;
        return r;
    };
    float* stats = (float*)alloc(4 * 256 * sizeof(float));
    float* ss = (float*)alloc(4 * 256 * sizeof(float));
    u16* featbf = (u16*)alloc((size_t)(N + 1) * 64 * 2);
    u16* w1 = (u16*)alloc((size_t)9 * 64 * 128 * 2);
    u16* w2 = (u16*)alloc((size_t)9 * 64 * 128 * 2);
    u16* w12 = (u16*)alloc((size_t)9 * 128 * 128 * 2);
    u16* w3 = (u16*)alloc((size_t)9 * 128 * 128 * 2);
    u16* zA = (u16*)alloc((size_t)N * 128 * 2);
    u16* zB = (u16*)alloc((size_t)N * 128 * 2);
    u16* y1 = (u16*)alloc((size_t)(N + 1) * 128 * 2);
    u16* y2 = (u16*)alloc((size_t)(N + 1) * 128 * 2);

    hipMemsetAsync(stats, 0, 4 * 256 * sizeof(float), stream);

    int totF = (N + 1) * 64;
    k_feat2bf<<<(totF / 8 + 255) / 256, 256, 0, stream>>>(feat, featbf, totF, N * 64);
    k_swz<<<(9 * 64 * 128 + 255) / 256, 256, 0, stream>>>(W1, w1, 64);
    k_swz<<<(9 * 64 * 128 + 255) / 256, 256, 0, stream>>>(W2, w2, 64);
    k_swz<<<(9 * 128 * 128 + 255) / 256, 256, 0, stream>>>(W12, w12, 128);
    k_swz<<<(9 * 128 * 128 + 255) / 256, 256, 0, stream>>>(W3, w3, 128);

    dim3 cgrid((N + 63) / 64, 2);
    // stage 1: cz=0: conv(nbr31, W1) -> zA/stats0 ; cz=1: conv(nbr13, W2) -> zB/stats1
    k_conv<64><<<cgrid, 512, 0, stream>>>(
        featbf, featbf, nbr31, nbr13, w1, w2, zA, zB, stats + 0, stats + 256, N);
    k_fin<<<1, 256, 0, stream>>>(stats, g0, b0, g1, b1, ss, N);
    int ablk = ((N + 1) * 16 + 255) / 256;
    k_aff<<<ablk, 256, 0, stream>>>(zA, ss + 0, y1, N);
    k_aff<<<ablk, 256, 0, stream>>>(zB, ss + 256, y2, N);
    // stage 2: cz=0: conv(y1, nbr13, W12) -> zA ; cz=1: conv(y2, nbr31, W3) -> zB
    k_conv<128><<<cgrid, 512, 0, stream>>>(
        y1, y2, nbr13, nbr31, w12, w3, zA, zB, stats + 512, stats + 768, N);
    k_fin<<<1, 256, 0, stream>>>(stats + 512, g02, b02, g2, b2, ss + 512, N);
    k_final<<<(N * 32 + 255) / 256, 256, 0, stream>>>(zA, zB, ss + 512, ss + 768, out, N);
}

// Round 10
// 424.051 us; speedup vs baseline: 1.1794x; 1.1794x over previous
//
#include <hip/hip_runtime.h>
#include <hip/hip_bf16.h>

typedef unsigned short u16;
typedef unsigned int u32;
typedef __attribute__((ext_vector_type(8))) short s16x8;
typedef __attribute__((ext_vector_type(4))) short s16x4;
typedef __attribute__((ext_vector_type(4))) float f32x4;

__device__ inline u16 f2bf(float x) {
    u32 u = __float_as_uint(x);
    u32 r = (u + 0x7fffu + ((u >> 16) & 1u)) >> 16;
    return (u16)r;
}
__device__ inline float bf2f(u16 u) {
    return __uint_as_float(((u32)u) << 16);
}

// ---- features f32 -> bf16, with zero sentinel row at index N ----
__global__ void k_feat2bf(const float* __restrict__ f, u16* __restrict__ o,
                          int total, int nvalid) {
    int i = (blockIdx.x * 256 + threadIdx.x) * 8;
    if (i >= total) return;
    s16x8 v;
#pragma unroll
    for (int j = 0; j < 8; ++j) {
        float x = (i + j < nvalid) ? f[i + j] : 0.f;
        v[j] = (short)f2bf(x);
    }
    *(s16x8*)(o + i) = v;
}

// ---- weight swizzle: W[9][cin][128] f32 -> MFMA-B fragment-packed bf16 ----
__global__ void k_swz(const float* __restrict__ W, u16* __restrict__ o, int cin) {
    int i = blockIdx.x * 256 + threadIdx.x;
    int total = 9 * cin * 128;
    if (i >= total) return;
    int j = i & 7;
    int l = (i >> 3) & 63;
    int fr = i >> 9;
    int ct = fr & 7;
    int rest = fr >> 3;
    int kcn = cin >> 5;
    int kc = rest % kcn;
    int t = rest / kcn;
    int kk = kc * 32 + (l >> 4) * 8 + j;
    int c = ct * 16 + (l & 15);
    o[i] = f2bf(W[(t * cin + kk) * 128 + c]);
}

// ---- gather-conv: 512 thr (8 waves x 32 voxels) x 32 output cols.
// XCD-grouped flat grid (4 column-quarter blocks of one (voxel-range, conv)
// group co-resident on one XCD). LDS-staged weights (all taps, no loop
// barriers). A-loads UNCONDITIONAL (skipped taps hit L1-hot sentinel row) and
// software-pipelined 1 tap ahead (double-buffered regs, static indexing);
// nbr indices rolled 2 ahead. Only the MFMA cluster is skipped per tap.
template <int CIN>
__global__ __launch_bounds__(512, 4) void k_conv(
    const u16* __restrict__ srcA, const u16* __restrict__ srcB,
    const int* __restrict__ nbrA, const int* __restrict__ nbrB,
    const u16* __restrict__ wA, const u16* __restrict__ wB,
    u16* __restrict__ zoutA, u16* __restrict__ zoutB,
    float* __restrict__ statsA, float* __restrict__ statsB,
    int N) {
    constexpr int KC = CIN / 32;
    constexpr int FR = 9 * KC * 2;    // staged frags (2 col-tiles of 16)
    __shared__ u16 wl[FR * 512];
    __shared__ float sstat[64];

    // ---- block-id remap: i = c8 + 8*(4q + h); group p = 8q + c8; quarter h ----
    const int nvr = (N + 255) >> 8;
    const int npairs = 2 * nvr;
    const int i = blockIdx.x;
    const int c8 = i & 7;
    const int m = i >> 3;
    const int h = m & 3;
    const int q = m >> 2;
    const int p = 8 * q + c8;
    if (p >= npairs) return;
    const int vr = p % nvr;
    const int cz = p / nvr;
    const int half = h;

    const u16* __restrict__ src = cz ? srcB : srcA;
    const int* __restrict__ nbr = cz ? nbrB : nbrA;
    const u16* __restrict__ w = cz ? wB : wA;
    u16* __restrict__ zout = cz ? zoutB : zoutA;
    float* __restrict__ stats = cz ? statsB : statsA;

    const int tid = threadIdx.x;

    // stage this quarter's weights for all taps; zero stats
    for (int ii = tid; ii < FR * 64; ii += 512) {
        int pp = ii & 63;
        int f = ii >> 6;          // (t*KC+kc)*2 + ctp
        int ctp = f & 1;
        int tk = f >> 1;
        s16x8 v = *(const s16x8*)(w + ((size_t)(tk * 8 + half * 2 + ctp)) * 512 + pp * 8);
        *(s16x8*)&wl[(size_t)f * 512 + pp * 8] = v;
    }
    if (tid < 64) sstat[tid] = 0.f;
    __syncthreads();

    const int lane = tid & 63;
    const int wv = tid >> 6;
    const int base = vr * 256 + wv * 32;
    const int am = lane & 15;
    const int grp = lane >> 4;
    const int vi0 = base + am;
    const int vi1 = base + 16 + am;
    const bool v0 = vi0 < N, v1 = vi1 < N;

    // rolling nbr state: rc = tap t, rn = tap t+1
    int rc0 = v0 ? nbr[vi0] : N;
    int rc1 = v1 ? nbr[vi1] : N;
    int rn0 = v0 ? nbr[N + vi0] : N;
    int rn1 = v1 ? nbr[N + vi1] : N;

    // A double-buffer; prologue fills buf 0 with tap 0
    s16x8 a0[2][KC], a1[2][KC];
    {
        const u16* sp0 = src + (size_t)rc0 * CIN + grp * 8;
        const u16* sp1 = src + (size_t)rc1 * CIN + grp * 8;
#pragma unroll
        for (int kc = 0; kc < KC; ++kc) {
            a0[0][kc] = *(const s16x8*)(sp0 + kc * 32);
            a1[0][kc] = *(const s16x8*)(sp1 + kc * 32);
        }
    }

    f32x4 acc0[2], acc1[2];
#pragma unroll
    for (int c = 0; c < 2; ++c) {
        acc0[c] = (f32x4){0.f, 0.f, 0.f, 0.f};
        acc1[c] = (f32x4){0.f, 0.f, 0.f, 0.f};
    }

#pragma unroll
    for (int t = 0; t < 9; ++t) {
        const int cur = t & 1, nxt = cur ^ 1;
        // issue tap t+1 A-loads (unconditional; sentinel rows are L1-hot)
        if (t < 8) {
            const u16* sp0 = src + (size_t)rn0 * CIN + grp * 8;
            const u16* sp1 = src + (size_t)rn1 * CIN + grp * 8;
#pragma unroll
            for (int kc = 0; kc < KC; ++kc) {
                a0[nxt][kc] = *(const s16x8*)(sp0 + kc * 32);
                a1[nxt][kc] = *(const s16x8*)(sp1 + kc * 32);
            }
        }
        // roll nbr 2 ahead
        int rf0 = N, rf1 = N;
        if (t < 7) {
            if (v0) rf0 = nbr[(t + 2) * N + vi0];
            if (v1) rf1 = nbr[(t + 2) * N + vi1];
        }
        // compute tap t (skip MFMAs only)
        if (__any((rc0 != N) || (rc1 != N))) {
            const u16* lb = wl + (size_t)t * (KC * 2) * 512 + lane * 8;
#pragma unroll
            for (int kc = 0; kc < KC; ++kc) {
#pragma unroll
                for (int c = 0; c < 2; ++c) {
                    s16x8 b = *(const s16x8*)(lb + (kc * 2 + c) * 512);
                    acc0[c] = __builtin_amdgcn_mfma_f32_16x16x32_bf16(a0[cur][kc], b, acc0[c], 0, 0, 0);
                    acc1[c] = __builtin_amdgcn_mfma_f32_16x16x32_bf16(a1[cur][kc], b, acc1[c], 0, 0, 0);
                }
            }
        }
        rc0 = rn0; rc1 = rn1;
        rn0 = rf0; rn1 = rf1;
    }

    // epilogue: lrelu, bf16 store, block-local stats
#pragma unroll
    for (int c = 0; c < 2; ++c) {
        float s = 0.f, qq = 0.f;
        const int col = half * 32 + c * 16 + am;
#pragma unroll
        for (int j = 0; j < 4; ++j) {
            {
                float x = acc0[c][j];
                float z = (x > 0.f) ? x : 0.01f * x;
                int row = base + grp * 4 + j;
                if (row < N) zout[(size_t)row * 128 + col] = f2bf(z);
                s += z;
                qq += z * z;
            }
            {
                float x = acc1[c][j];
                float z = (x > 0.f) ? x : 0.01f * x;
                int row = base + 16 + grp * 4 + j;
                if (row < N) zout[(size_t)row * 128 + col] = f2bf(z);
                s += z;
                qq += z * z;
            }
        }
        s += __shfl_xor(s, 16);
        qq += __shfl_xor(qq, 16);
        s += __shfl_xor(s, 32);
        qq += __shfl_xor(qq, 32);
        if (lane < 16) {
            atomicAdd(&sstat[c * 16 + am], s);
            atomicAdd(&sstat[32 + c * 16 + am], qq);
        }
    }
    __syncthreads();
    if (tid < 32) {
        int cg = half * 32 + tid;
        atomicAdd(stats + cg, sstat[tid]);
        atomicAdd(stats + 128 + cg, sstat[32 + tid]);
    }
}

// ---- finalize two BN stat sets -> per-channel scale/shift ----
__global__ void k_fin(const float* __restrict__ stats,
                      const float* __restrict__ g0, const float* __restrict__ b0,
                      const float* __restrict__ g1, const float* __restrict__ b1,
                      float* __restrict__ ss, int N) {
    int tid = threadIdx.x;
    int set = tid >> 7, c = tid & 127;
    const float* st = stats + set * 256;
    float invN = 1.f / (float)N;
    float m = st[c] * invN;
    float var = st[128 + c] * invN - m * m;
    const float* g = set ? g1 : g0;
    const float* b = set ? b1 : b0;
    float sc = g[c] * rsqrtf(var + 1e-5f);
    float sh = b[c] - m * sc;
    float* o = ss + set * 256;
    o[c] = sc;
    o[128 + c] = sh;
}

// ---- y = z*scale + shift (bf16 out, with zero sentinel row N) ----
__global__ void k_aff(const u16* __restrict__ z, const float* __restrict__ ss,
                      u16* __restrict__ y, int N) {
    int v = blockIdx.x * 256 + threadIdx.x;
    int total = (N + 1) * 16;
    if (v >= total) return;
    int row = v >> 4;
    int cb = (v & 15) * 8;
    s16x8 o;
    if (row < N) {
        s16x8 zi = *(const s16x8*)(z + (size_t)row * 128 + cb);
#pragma unroll
        for (int j = 0; j < 8; ++j) {
            float x = bf2f((u16)zi[j]);
            float r = x * ss[cb + j] + ss[128 + cb + j];
            o[j] = (short)f2bf(r);
        }
    } else {
        o = (s16x8){0, 0, 0, 0, 0, 0, 0, 0};
    }
    *(s16x8*)(y + (size_t)row * 128 + cb) = o;
}

// ---- out = bn(z3) + bn(z4), f32 ----
__global__ void k_final(const u16* __restrict__ z3, const u16* __restrict__ z4,
                        const float* __restrict__ ssA, const float* __restrict__ ssB,
                        float* __restrict__ out, int N) {
    int v = blockIdx.x * 256 + threadIdx.x;
    int total = N * 32;
    if (v >= total) return;
    int row = v >> 5;
    int cb = (v & 31) * 4;
    s16x4 a = *(const s16x4*)(z3 + (size_t)row * 128 + cb);
    s16x4 b = *(const s16x4*)(z4 + (size_t)row * 128 + cb);
    f32x4 o;
#pragma unroll
    for (int j = 0; j < 4; ++j) {
        int c = cb + j;
        o[j] = bf2f((u16)a[j]) * ssA[c] + ssA[128 + c] +
               bf2f((u16)b[j]) * ssB[c] + ssB[128 + c];
    }
    *(f32x4*)(out + (size_t)row * 128 + cb) = o;
}

extern "C" void kernel_launch(void* const* d_in, const int* in_sizes, int n_in,
                              void* d_out, int out_size, void* d_ws, size_t ws_size,
                              hipStream_t stream) {
    const float* feat = (const float*)d_in[0];
    const int* nbr31 = (const int*)d_in[1];
    const int* nbr13 = (const int*)d_in[2];
    const float* W1 = (const float*)d_in[3];
    const float* W12 = (const float*)d_in[4];
    const float* W2 = (const float*)d_in[5];
    const float* W3 = (const float*)d_in[6];
    const float* g0 = (const float*)d_in[7];
    const float* b0 = (const float*)d_in[8];
    const float* g02 = (const float*)d_in[9];
    const float* b02 = (const float*)d_in[10];
    const float* g1 = (const float*)d_in[11];
    const float* b1 = (const float*)d_in[12];
    const float* g2 = (const float*)d_in[13];
    const float* b2 = (const float*)d_in[14];
    float* out = (float*)d_out;
    const int N = in_sizes[0] / 64;  // 200000

    char* p = (char*)d_ws;
    auto alloc = [&](size_t bytes) {
        char* r = p;
        p += (bytes + 255) & ~(size_t)255;
        return r;
    };
    float* stats = (float*)alloc(4 * 256 * sizeof(float));
    float* ss = (float*)alloc(4 * 256 * sizeof(float));
    u16* featbf = (u16*)alloc((size_t)(N + 1) * 64 * 2);
    u16* w1 = (u16*)alloc((size_t)9 * 64 * 128 * 2);
    u16* w2 = (u16*)alloc((size_t)9 * 64 * 128 * 2);
    u16* w12 = (u16*)alloc((size_t)9 * 128 * 128 * 2);
    u16* w3 = (u16*)alloc((size_t)9 * 128 * 128 * 2);
    u16* zA = (u16*)alloc((size_t)N * 128 * 2);
    u16* zB = (u16*)alloc((size_t)N * 128 * 2);
    u16* y1 = (u16*)alloc((size_t)(N + 1) * 128 * 2);
    u16* y2 = (u16*)alloc((size_t)(N + 1) * 128 * 2);

    hipMemsetAsync(stats, 0, 4 * 256 * sizeof(float), stream);

    int totF = (N + 1) * 64;
    k_feat2bf<<<(totF / 8 + 255) / 256, 256, 0, stream>>>(feat, featbf, totF, N * 64);
    k_swz<<<(9 * 64 * 128 + 255) / 256, 256, 0, stream>>>(W1, w1, 64);
    k_swz<<<(9 * 64 * 128 + 255) / 256, 256, 0, stream>>>(W2, w2, 64);
    k_swz<<<(9 * 128 * 128 + 255) / 256, 256, 0, stream>>>(W12, w12, 128);
    k_swz<<<(9 * 128 * 128 + 255) / 256, 256, 0, stream>>>(W3, w3, 128);

    // flat grid with XCD-grouping remap: 8 * 4 * ceil(npairs/8) blocks
    int nvr = (N + 255) / 256;
    int npairs = 2 * nvr;
    int nblk = 8 * 4 * ((npairs + 7) / 8);

    // stage 1: cz=0: conv(nbr31, W1) -> zA/stats0 ; cz=1: conv(nbr13, W2) -> zB/stats1
    k_conv<64><<<nblk, 512, 0, stream>>>(
        featbf, featbf, nbr31, nbr13, w1, w2, zA, zB, stats + 0, stats + 256, N);
    k_fin<<<1, 256, 0, stream>>>(stats, g0, b0, g1, b1, ss, N);
    int ablk = ((N + 1) * 16 + 255) / 256;
    k_aff<<<ablk, 256, 0, stream>>>(zA, ss + 0, y1, N);
    k_aff<<<ablk, 256, 0, stream>>>(zB, ss + 256, y2, N);
    // stage 2: cz=0: conv(y1, nbr13, W12) -> zA ; cz=1: conv(y2, nbr31, W3) -> zB
    k_conv<128><<<nblk, 512, 0, stream>>>(
        y1, y2, nbr13, nbr31, w12, w3, zA, zB, stats + 512, stats + 768, N);
    k_fin<<<1, 256, 0, stream>>>(stats + 512, g02, b02, g2, b2, ss + 512, N);
    k_final<<<(N * 32 + 255) / 256, 256, 0, stream>>>(zA, zB, ss + 512, ss + 768, out, N);
}

// Round 11
// 401.332 us; speedup vs baseline: 1.2461x; 1.0566x over previous
//
#include <hip/hip_runtime.h>
#include <hip/hip_bf16.h>

typedef unsigned short u16;
typedef unsigned int u32;
typedef unsigned long long u64;
typedef __attribute__((ext_vector_type(8))) short s16x8;
typedef __attribute__((ext_vector_type(4))) short s16x4;
typedef __attribute__((ext_vector_type(4))) float f32x4;

__device__ inline u16 f2bf(float x) {
    u32 u = __float_as_uint(x);
    u32 r = (u + 0x7fffu + ((u >> 16) & 1u)) >> 16;
    return (u16)r;
}
__device__ inline float bf2f(u16 u) {
    return __uint_as_float(((u32)u) << 16);
}

// ---- features f32 -> bf16, with zero sentinel row at index N ----
__global__ void k_feat2bf(const float* __restrict__ f, u16* __restrict__ o,
                          int total, int nvalid) {
    int i = (blockIdx.x * 256 + threadIdx.x) * 8;
    if (i >= total) return;
    s16x8 v;
#pragma unroll
    for (int j = 0; j < 8; ++j) {
        float x = (i + j < nvalid) ? f[i + j] : 0.f;
        v[j] = (short)f2bf(x);
    }
    *(s16x8*)(o + i) = v;
}

// ---- weight swizzle: W[9][cin][128] f32 -> MFMA-B fragment-packed bf16 ----
__global__ void k_swz(const float* __restrict__ W, u16* __restrict__ o, int cin) {
    int i = blockIdx.x * 256 + threadIdx.x;
    int total = 9 * cin * 128;
    if (i >= total) return;
    int j = i & 7;
    int l = (i >> 3) & 63;
    int fr = i >> 9;
    int ct = fr & 7;
    int rest = fr >> 3;
    int kcn = cin >> 5;
    int kc = rest % kcn;
    int t = rest / kcn;
    int kk = kc * 32 + (l >> 4) * 8 + j;
    int c = ct * 16 + (l & 15);
    o[i] = f2bf(W[(t * cin + kk) * 128 + c]);
}

// ---- gather-conv: 512 thr (8 waves x 64 voxels) x 32 output cols.
// Wave = 64 voxels = 4 MFMA row-groups; each B ds_read feeds up to 4
// conditional (wave-uniform) MFMAs -> ~2.2x less LDS traffic than R4.
// nbr: ONE full-wave load + 4 __shfl row-broadcasts; one ballot -> 4 e_g.
// Gathers conditional per group (skipped group-taps cost nothing).
// Weight LDS: all taps for this 32-col quarter (72/36 KB), no loop barriers.
// XCD-grouped remap: 4 quarter-blocks of one (vr, conv) adjacent + same mod 8.
template <int CIN>
__global__ __launch_bounds__(512, 4) void k_conv(
    const u16* __restrict__ srcA, const u16* __restrict__ srcB,
    const int* __restrict__ nbrA, const int* __restrict__ nbrB,
    const u16* __restrict__ wA, const u16* __restrict__ wB,
    u16* __restrict__ zoutA, u16* __restrict__ zoutB,
    float* __restrict__ statsA, float* __restrict__ statsB,
    int N) {
    constexpr int KC = CIN / 32;
    constexpr int FR = 9 * KC * 2;    // staged frags (2 col-tiles of 16)
    __shared__ u16 wl[FR * 512];
    __shared__ float sstat[64];

    // ---- block-id remap: i = c8 + 8*(4q + h); pair p = 8q + c8; quarter h ----
    const int nvr = (N + 511) >> 9;
    const int npairs = 2 * nvr;
    const int i = blockIdx.x;
    const int c8 = i & 7;
    const int m = i >> 3;
    const int h = m & 3;
    const int q = m >> 2;
    const int p = 8 * q + c8;
    if (p >= npairs) return;
    const int vr = p % nvr;
    const int cz = p / nvr;
    const int quarter = h;

    const u16* __restrict__ src = cz ? srcB : srcA;
    const int* __restrict__ nbr = cz ? nbrB : nbrA;
    const u16* __restrict__ w = cz ? wB : wA;
    u16* __restrict__ zout = cz ? zoutB : zoutA;
    float* __restrict__ stats = cz ? statsB : statsA;

    const int tid = threadIdx.x;

    // stage this quarter's weights for all taps; zero stats
    for (int ii = tid; ii < FR * 64; ii += 512) {
        int pp = ii & 63;
        int f = ii >> 6;          // (t*KC+kc)*2 + ctp
        int ctp = f & 1;
        int tk = f >> 1;
        s16x8 v = *(const s16x8*)(w + ((size_t)(tk * 8 + quarter * 2 + ctp)) * 512 + pp * 8);
        *(s16x8*)&wl[(size_t)f * 512 + pp * 8] = v;
    }
    if (tid < 64) sstat[tid] = 0.f;
    __syncthreads();

    const int lane = tid & 63;
    const int wv = tid >> 6;
    const int base = vr * 512 + wv * 64;   // 64 voxels per wave
    const int am = lane & 15;
    const int grp = lane >> 4;
    const int vi = base + lane;
    const bool vok = vi < N;

    int rc = vok ? nbr[vi] : N;            // tap 0 nbr (center of rolling pair)

    f32x4 acc[4][2];
#pragma unroll
    for (int g = 0; g < 4; ++g)
#pragma unroll
        for (int c = 0; c < 2; ++c) acc[g][c] = (f32x4){0.f, 0.f, 0.f, 0.f};

#pragma unroll
    for (int t = 0; t < 9; ++t) {
        // prefetch next tap's nbr (one full-wave load)
        int rn = N;
        if (t < 8 && vok) rn = nbr[(t + 1) * N + vi];

        u64 mask = __ballot(rc != N);
        const bool e0 = (mask & 0xFFFFull) != 0;
        const bool e1 = (mask & 0xFFFF0000ull) != 0;
        const bool e2 = (mask & 0xFFFF00000000ull) != 0;
        const bool e3 = (mask & 0xFFFF000000000000ull) != 0;

        // conditional batched gathers per 16-row group (row idx via shfl)
        s16x8 a[4][KC];
        if (e0) {
            int rg = __shfl(rc, am);
            const u16* sp = src + (size_t)rg * CIN + grp * 8;
#pragma unroll
            for (int kc = 0; kc < KC; ++kc) a[0][kc] = *(const s16x8*)(sp + kc * 32);
        }
        if (e1) {
            int rg = __shfl(rc, 16 + am);
            const u16* sp = src + (size_t)rg * CIN + grp * 8;
#pragma unroll
            for (int kc = 0; kc < KC; ++kc) a[1][kc] = *(const s16x8*)(sp + kc * 32);
        }
        if (e2) {
            int rg = __shfl(rc, 32 + am);
            const u16* sp = src + (size_t)rg * CIN + grp * 8;
#pragma unroll
            for (int kc = 0; kc < KC; ++kc) a[2][kc] = *(const s16x8*)(sp + kc * 32);
        }
        if (e3) {
            int rg = __shfl(rc, 48 + am);
            const u16* sp = src + (size_t)rg * CIN + grp * 8;
#pragma unroll
            for (int kc = 0; kc < KC; ++kc) a[3][kc] = *(const s16x8*)(sp + kc * 32);
        }

        // compute: each B frag read ONCE, feeds up to 4 group-MFMAs
        const u16* lb = wl + (size_t)t * (KC * 2) * 512 + lane * 8;
#pragma unroll
        for (int kc = 0; kc < KC; ++kc) {
            s16x8 b0 = *(const s16x8*)(lb + (size_t)(kc * 2 + 0) * 512);
            s16x8 b1 = *(const s16x8*)(lb + (size_t)(kc * 2 + 1) * 512);
            if (e0) {
                acc[0][0] = __builtin_amdgcn_mfma_f32_16x16x32_bf16(a[0][kc], b0, acc[0][0], 0, 0, 0);
                acc[0][1] = __builtin_amdgcn_mfma_f32_16x16x32_bf16(a[0][kc], b1, acc[0][1], 0, 0, 0);
            }
            if (e1) {
                acc[1][0] = __builtin_amdgcn_mfma_f32_16x16x32_bf16(a[1][kc], b0, acc[1][0], 0, 0, 0);
                acc[1][1] = __builtin_amdgcn_mfma_f32_16x16x32_bf16(a[1][kc], b1, acc[1][1], 0, 0, 0);
            }
            if (e2) {
                acc[2][0] = __builtin_amdgcn_mfma_f32_16x16x32_bf16(a[2][kc], b0, acc[2][0], 0, 0, 0);
                acc[2][1] = __builtin_amdgcn_mfma_f32_16x16x32_bf16(a[2][kc], b1, acc[2][1], 0, 0, 0);
            }
            if (e3) {
                acc[3][0] = __builtin_amdgcn_mfma_f32_16x16x32_bf16(a[3][kc], b0, acc[3][0], 0, 0, 0);
                acc[3][1] = __builtin_amdgcn_mfma_f32_16x16x32_bf16(a[3][kc], b1, acc[3][1], 0, 0, 0);
            }
        }
        rc = rn;
    }

    // epilogue: lrelu, bf16 store, block-local stats
#pragma unroll
    for (int g = 0; g < 4; ++g) {
#pragma unroll
        for (int c = 0; c < 2; ++c) {
            float s = 0.f, qq = 0.f;
            const int col = quarter * 32 + c * 16 + am;
#pragma unroll
            for (int j = 0; j < 4; ++j) {
                float x = acc[g][c][j];
                float z = (x > 0.f) ? x : 0.01f * x;
                int row = base + g * 16 + grp * 4 + j;
                if (row < N) zout[(size_t)row * 128 + col] = f2bf(z);
                s += z;
                qq += z * z;
            }
            s += __shfl_xor(s, 16);
            qq += __shfl_xor(qq, 16);
            s += __shfl_xor(s, 32);
            qq += __shfl_xor(qq, 32);
            if (lane < 16) {
                atomicAdd(&sstat[c * 16 + am], s);
                atomicAdd(&sstat[32 + c * 16 + am], qq);
            }
        }
    }
    __syncthreads();
    if (tid < 32) {
        int cg = quarter * 32 + tid;
        atomicAdd(stats + cg, sstat[tid]);
        atomicAdd(stats + 128 + cg, sstat[32 + tid]);
    }
}

// ---- finalize two BN stat sets -> per-channel scale/shift ----
__global__ void k_fin(const float* __restrict__ stats,
                      const float* __restrict__ g0, const float* __restrict__ b0,
                      const float* __restrict__ g1, const float* __restrict__ b1,
                      float* __restrict__ ss, int N) {
    int tid = threadIdx.x;
    int set = tid >> 7, c = tid & 127;
    const float* st = stats + set * 256;
    float invN = 1.f / (float)N;
    float m = st[c] * invN;
    float var = st[128 + c] * invN - m * m;
    const float* g = set ? g1 : g0;
    const float* b = set ? b1 : b0;
    float sc = g[c] * rsqrtf(var + 1e-5f);
    float sh = b[c] - m * sc;
    float* o = ss + set * 256;
    o[c] = sc;
    o[128 + c] = sh;
}

// ---- y = z*scale + shift (bf16 out, with zero sentinel row N) ----
__global__ void k_aff(const u16* __restrict__ z, const float* __restrict__ ss,
                      u16* __restrict__ y, int N) {
    int v = blockIdx.x * 256 + threadIdx.x;
    int total = (N + 1) * 16;
    if (v >= total) return;
    int row = v >> 4;
    int cb = (v & 15) * 8;
    s16x8 o;
    if (row < N) {
        s16x8 zi = *(const s16x8*)(z + (size_t)row * 128 + cb);
#pragma unroll
        for (int j = 0; j < 8; ++j) {
            float x = bf2f((u16)zi[j]);
            float r = x * ss[cb + j] + ss[128 + cb + j];
            o[j] = (short)f2bf(r);
        }
    } else {
        o = (s16x8){0, 0, 0, 0, 0, 0, 0, 0};
    }
    *(s16x8*)(y + (size_t)row * 128 + cb) = o;
}

// ---- out = bn(z3) + bn(z4), f32 ----
__global__ void k_final(const u16* __restrict__ z3, const u16* __restrict__ z4,
                        const float* __restrict__ ssA, const float* __restrict__ ssB,
                        float* __restrict__ out, int N) {
    int v = blockIdx.x * 256 + threadIdx.x;
    int total = N * 32;
    if (v >= total) return;
    int row = v >> 5;
    int cb = (v & 31) * 4;
    s16x4 a = *(const s16x4*)(z3 + (size_t)row * 128 + cb);
    s16x4 b = *(const s16x4*)(z4 + (size_t)row * 128 + cb);
    f32x4 o;
#pragma unroll
    for (int j = 0; j < 4; ++j) {
        int c = cb + j;
        o[j] = bf2f((u16)a[j]) * ssA[c] + ssA[128 + c] +
               bf2f((u16)b[j]) * ssB[c] + ssB[128 + c];
    }
    *(f32x4*)(out + (size_t)row * 128 + cb) = o;
}

extern "C" void kernel_launch(void* const* d_in, const int* in_sizes, int n_in,
                              void* d_out, int out_size, void* d_ws, size_t ws_size,
                              hipStream_t stream) {
    const float* feat = (const float*)d_in[0];
    const int* nbr31 = (const int*)d_in[1];
    const int* nbr13 = (const int*)d_in[2];
    const float* W1 = (const float*)d_in[3];
    const float* W12 = (const float*)d_in[4];
    const float* W2 = (const float*)d_in[5];
    const float* W3 = (const float*)d_in[6];
    const float* g0 = (const float*)d_in[7];
    const float* b0 = (const float*)d_in[8];
    const float* g02 = (const float*)d_in[9];
    const float* b02 = (const float*)d_in[10];
    const float* g1 = (const float*)d_in[11];
    const float* b1 = (const float*)d_in[12];
    const float* g2 = (const float*)d_in[13];
    const float* b2 = (const float*)d_in[14];
    float* out = (float*)d_out;
    const int N = in_sizes[0] / 64;  // 200000

    char* p = (char*)d_ws;
    auto alloc = [&](size_t bytes) {
        char* r = p;
        p += (bytes + 255) & ~(size_t)255;
        return r;
    };
    float* stats = (float*)alloc(4 * 256 * sizeof(float));
    float* ss = (float*)alloc(4 * 256 * sizeof(float));
    u16* featbf = (u16*)alloc((size_t)(N + 1) * 64 * 2);
    u16* w1 = (u16*)alloc((size_t)9 * 64 * 128 * 2);
    u16* w2 = (u16*)alloc((size_t)9 * 64 * 128 * 2);
    u16* w12 = (u16*)alloc((size_t)9 * 128 * 128 * 2);
    u16* w3 = (u16*)alloc((size_t)9 * 128 * 128 * 2);
    u16* zA = (u16*)alloc((size_t)N * 128 * 2);
    u16* zB = (u16*)alloc((size_t)N * 128 * 2);
    u16* y1 = (u16*)alloc((size_t)(N + 1) * 128 * 2);
    u16* y2 = (u16*)alloc((size_t)(N + 1) * 128 * 2);

    hipMemsetAsync(stats, 0, 4 * 256 * sizeof(float), stream);

    int totF = (N + 1) * 64;
    k_feat2bf<<<(totF / 8 + 255) / 256, 256, 0, stream>>>(feat, featbf, totF, N * 64);
    k_swz<<<(9 * 64 * 128 + 255) / 256, 256, 0, stream>>>(W1, w1, 64);
    k_swz<<<(9 * 64 * 128 + 255) / 256, 256, 0, stream>>>(W2, w2, 64);
    k_swz<<<(9 * 128 * 128 + 255) / 256, 256, 0, stream>>>(W12, w12, 128);
    k_swz<<<(9 * 128 * 128 + 255) / 256, 256, 0, stream>>>(W3, w3, 128);

    // flat grid with XCD-grouping remap: 8 * 4 * ceil(npairs/8) blocks
    int nvr = (N + 511) / 512;
    int npairs = 2 * nvr;
    int nblk = 8 * 4 * ((npairs + 7) / 8);

    // stage 1: cz=0: conv(nbr31, W1) -> zA/stats0 ; cz=1: conv(nbr13, W2) -> zB/stats1
    k_conv<64><<<nblk, 512, 0, stream>>>(
        featbf, featbf, nbr31, nbr13, w1, w2, zA, zB, stats + 0, stats + 256, N);
    k_fin<<<1, 256, 0, stream>>>(stats, g0, b0, g1, b1, ss, N);
    int ablk = ((N + 1) * 16 + 255) / 256;
    k_aff<<<ablk, 256, 0, stream>>>(zA, ss + 0, y1, N);
    k_aff<<<ablk, 256, 0, stream>>>(zB, ss + 256, y2, N);
    // stage 2: cz=0: conv(y1, nbr13, W12) -> zA ; cz=1: conv(y2, nbr31, W3) -> zB
    k_conv<128><<<nblk, 512, 0, stream>>>(
        y1, y2, nbr13, nbr31, w12, w3, zA, zB, stats + 512, stats + 768, N);
    k_fin<<<1, 256, 0, stream>>>(stats + 512, g02, b02, g2, b2, ss + 512, N);
    k_final<<<(N * 32 + 255) / 256, 256, 0, stream>>>(zA, zB, ss + 512, ss + 768, out, N);
}